// Round 6
// baseline (845.446 us; speedup 1.0000x reference)
//
#include <hip/hip_runtime.h>

typedef unsigned short u16;
typedef unsigned int   u32;
typedef __bf16  bf16x8 __attribute__((ext_vector_type(8)));
typedef float   f32x4  __attribute__((ext_vector_type(4)));
typedef unsigned int u32x4 __attribute__((ext_vector_type(4)));
typedef unsigned int u32x2 __attribute__((ext_vector_type(2)));

__device__ __forceinline__ float bf2f(u16 h){ return __uint_as_float(((u32)h)<<16); }
__device__ __forceinline__ u16 f2bf(float f){
  u32 u = __float_as_uint(f);
  u += 0x7FFFu + ((u>>16)&1u);
  return (u16)(u>>16);
}
__device__ __forceinline__ f32x4 mfma16(bf16x8 a, bf16x8 b, f32x4 c){
  return __builtin_amdgcn_mfma_f32_16x16x32_bf16(a,b,c,0,0,0);
}
// async global->LDS, 16B per lane (dest = wave-uniform base + lane*16)
__device__ __forceinline__ void ld16_lds(const u16* g, u16* l){
  __builtin_amdgcn_global_load_lds((const __attribute__((address_space(1))) u32*)g,
                                   (__attribute__((address_space(3))) u32*)l, 16, 0, 0);
}

// ---------------- fp32 -> bf16 convert (4 elems/thread) ----------------
__global__ __launch_bounds__(256) void cvt_kernel(const float* __restrict__ in,
                                                  u16* __restrict__ out, int n4){
  int i = blockIdx.x*256 + threadIdx.x;
  if (i < n4){
    float4 v = ((const float4*)in)[i];
    u32 p0 = (u32)f2bf(v.x) | ((u32)f2bf(v.y)<<16);
    u32 p1 = (u32)f2bf(v.z) | ((u32)f2bf(v.w)<<16);
    u32x2 pv = {p0, p1};
    *(u32x2*)(out + (size_t)i*4) = pv;
  }
}

// ---------------- dt = softplus(u @ W_A^T) in fp32 (full 16384 tokens) ----------------
__global__ __launch_bounds__(256) void dt_kernel(const float* __restrict__ u,
                                                 const float* __restrict__ Win,
                                                 float* __restrict__ dtb){
  __shared__ float us[8][1028];
  const int tid = threadIdx.x;
  const size_t t0 = (size_t)blockIdx.x*8;
  for (int i=tid; i<2048; i+=256){
    int row = i>>8, col = (i&255)*4;
    *(float4*)&us[row][col] = *(const float4*)(u + (t0+row)*1024 + col);
  }
  __syncthreads();
  const int tok = tid & 7, h = tid >> 3;
  const float* wp = Win + (size_t)(6144+h)*1024;
  float s0=0.f,s1=0.f,s2=0.f,s3=0.f;
  for (int k=0;k<1024;k+=4){
    float4 a  = *(const float4*)&us[tok][k];
    float4 wv = *(const float4*)&wp[k];
    s0 += a.x*wv.x; s1 += a.y*wv.y; s2 += a.z*wv.z; s3 += a.w*wv.w;
  }
  float s = (s0+s1)+(s2+s3);
  dtb[(t0+tok)*32 + h] = (s > 15.f) ? s : log1pf(expf(s));
}

// ---------------- in_proj GEMM (bf16 NT, 128x128 tile, BK=64, double-buffered) ----------------
// R5 baseline + LDS double-buffer with stage-before-compute (T3 minimal 2-phase):
// per K-step: STG(next tile -> other buf); CMP(cur buf); __syncthreads().
// The mid-step barrier both protects the LDS WAR (buffer about to be overwritten was
// just read, lgkm drained) and drains the PREVIOUS stage's vmcnt -- so every staged
// load has a full compute phase (~600cy) in flight before its drain, instead of the
// old stage->drain->compute order which exposed the whole load latency every K-step.
// Swizzle (R5-verified, conflicts=0): slot' = slot ^ (row&7); inverse-swizzled global
// SOURCE (global_load_lds dest linear) + swizzled read address.
__global__ __launch_bounds__(256,2) void gemm_in(const u16* __restrict__ A,
                                                 const u16* __restrict__ Bw,
                                                 u16* __restrict__ out0,
                                                 u16* __restrict__ out1,
                                                 const float* __restrict__ zb){
  __shared__ u16 As[2*128*64];
  __shared__ u16 Bs[2*128*64];
  const int tid  = threadIdx.x;
  const int lane = tid & 63;
  const int w = tid >> 6, wm = w >> 1, wn = w & 1;
  const int quad = lane >> 4, l15 = lane & 15;
  const size_t m0 = (size_t)blockIdx.y*128, n0 = (size_t)blockIdx.x*128;

  f32x4 acc[4][4];
  #pragma unroll
  for (int i=0;i<4;i++)
    #pragma unroll
    for (int j=0;j<4;j++){ f32x4 z = {0.f,0.f,0.f,0.f}; acc[i][j] = z; }

  // staging: wave w covers rows [w*32, w*32+32), 4 chunks of 8 rows (1KB each).
  // lane l -> LDS row w*32 + c*8 + (l>>3), slot (l&7); source slot (l&7) ^ (l>>3).
  const int srow    = w*32 + (lane>>3);
  const int scol_sw = ((lane&7) ^ (lane>>3))*8;
  const u16* gA = A  + (m0+srow)*1024 + scol_sw;
  const u16* gB = Bw + (n0+srow)*1024 + scol_sw;
  const int lofs = w*2048;

#define STG(BUF) do{                                   \
    u16* la = As + (BUF)*8192 + lofs;                  \
    u16* lb = Bs + (BUF)*8192 + lofs;                  \
    ld16_lds(gA,         la);                          \
    ld16_lds(gA +  8192, la + 512);                    \
    ld16_lds(gA + 16384, la + 1024);                   \
    ld16_lds(gA + 24576, la + 1536);                   \
    ld16_lds(gB,         lb);                          \
    ld16_lds(gB +  8192, lb + 512);                    \
    ld16_lds(gB + 16384, lb + 1024);                   \
    ld16_lds(gB + 24576, lb + 1536);                   \
    gA += 64; gB += 64; }while(0)

#define CMP(BUF) do{                                                            \
    _Pragma("unroll")                                                           \
    for (int kk=0;kk<2;kk++){                                                   \
      bf16x8 av[4], bv[4];                                                      \
      _Pragma("unroll")                                                         \
      for (int mi=0;mi<4;mi++){                                                 \
        int row = wm*64+mi*16+l15;                                              \
        av[mi] = *(const bf16x8*)&As[(BUF)*8192 + row*64 + (((kk*4+quad) ^ (l15&7))*8)]; \
      }                                                                         \
      _Pragma("unroll")                                                         \
      for (int ni=0;ni<4;ni++){                                                 \
        int row = wn*64+ni*16+l15;                                              \
        bv[ni] = *(const bf16x8*)&Bs[(BUF)*8192 + row*64 + (((kk*4+quad) ^ (l15&7))*8)]; \
      }                                                                         \
      _Pragma("unroll")                                                         \
      for (int mi=0;mi<4;mi++)                                                  \
        _Pragma("unroll")                                                       \
        for (int ni=0;ni<4;ni++)                                                \
          acc[mi][ni] = mfma16(av[mi], bv[ni], acc[mi][ni]);                    \
    } }while(0)

  STG(0);                    // tile 0
  __syncthreads();
  #pragma unroll 1
  for (int t=0; t<14; t+=2){
    STG(1);                  // tile t+1
    CMP(0);                  // tile t
    __syncthreads();
    STG(0);                  // tile t+2
    CMP(1);                  // tile t+1
    __syncthreads();
  }
  STG(1);                    // tile 15
  CMP(0);                    // tile 14
  __syncthreads();
  CMP(1);                    // tile 15

#undef STG
#undef CMP

  #pragma unroll
  for (int mi=0;mi<4;mi++){
    #pragma unroll
    for (int ni=0;ni<4;ni++){
      #pragma unroll
      for (int r=0;r<4;r++){
        size_t row = m0 + wm*64 + mi*16 + quad*4 + r;
        int    col = (int)n0 + wn*64 + ni*16 + l15;
        float v = acc[mi][ni][r];
        if (col < 5120){
          out0[row*5120 + col] = f2bf(v);
        } else {
          int ch = col - 5120;
          float z = v + zb[ch];
          float sg = z / (1.f + __expf(-z));
          out1[row*1024 + ch] = f2bf(sg);
        }
      }
    }
  }
}

// ---------------- out GEMM (bf16 NT, BK=64, double-buffered, fp32 store) ----------------
__global__ __launch_bounds__(256,2) void gemm_out(const u16* __restrict__ A,
                                                  const u16* __restrict__ Bw,
                                                  float* __restrict__ out0){
  __shared__ u16 As[2*128*64];
  __shared__ u16 Bs[2*128*64];
  const int tid  = threadIdx.x;
  const int lane = tid & 63;
  const int w = tid >> 6, wm = w >> 1, wn = w & 1;
  const int quad = lane >> 4, l15 = lane & 15;
  const size_t m0 = (size_t)blockIdx.y*128, n0 = (size_t)blockIdx.x*128;

  f32x4 acc[4][4];
  #pragma unroll
  for (int i=0;i<4;i++)
    #pragma unroll
    for (int j=0;j<4;j++){ f32x4 z = {0.f,0.f,0.f,0.f}; acc[i][j] = z; }

  const int srow    = w*32 + (lane>>3);
  const int scol_sw = ((lane&7) ^ (lane>>3))*8;
  const u16* gA = A  + (m0+srow)*1024 + scol_sw;
  const u16* gB = Bw + (n0+srow)*1024 + scol_sw;
  const int lofs = w*2048;

#define STG(BUF) do{                                   \
    u16* la = As + (BUF)*8192 + lofs;                  \
    u16* lb = Bs + (BUF)*8192 + lofs;                  \
    ld16_lds(gA,         la);                          \
    ld16_lds(gA +  8192, la + 512);                    \
    ld16_lds(gA + 16384, la + 1024);                   \
    ld16_lds(gA + 24576, la + 1536);                   \
    ld16_lds(gB,         lb);                          \
    ld16_lds(gB +  8192, lb + 512);                    \
    ld16_lds(gB + 16384, lb + 1024);                   \
    ld16_lds(gB + 24576, lb + 1536);                   \
    gA += 64; gB += 64; }while(0)

#define CMP(BUF) do{                                                            \
    _Pragma("unroll")                                                           \
    for (int kk=0;kk<2;kk++){                                                   \
      bf16x8 av[4], bv[4];                                                      \
      _Pragma("unroll")                                                         \
      for (int mi=0;mi<4;mi++){                                                 \
        int row = wm*64+mi*16+l15;                                              \
        av[mi] = *(const bf16x8*)&As[(BUF)*8192 + row*64 + (((kk*4+quad) ^ (l15&7))*8)]; \
      }                                                                         \
      _Pragma("unroll")                                                         \
      for (int ni=0;ni<4;ni++){                                                 \
        int row = wn*64+ni*16+l15;                                              \
        bv[ni] = *(const bf16x8*)&Bs[(BUF)*8192 + row*64 + (((kk*4+quad) ^ (l15&7))*8)]; \
      }                                                                         \
      _Pragma("unroll")                                                         \
      for (int mi=0;mi<4;mi++)                                                  \
        _Pragma("unroll")                                                       \
        for (int ni=0;ni<4;ni++)                                                \
          acc[mi][ni] = mfma16(av[mi], bv[ni], acc[mi][ni]);                    \
    } }while(0)

  STG(0);
  __syncthreads();
  #pragma unroll 1
  for (int t=0; t<14; t+=2){
    STG(1);
    CMP(0);
    __syncthreads();
    STG(0);
    CMP(1);
    __syncthreads();
  }
  STG(1);
  CMP(0);
  __syncthreads();
  CMP(1);

#undef STG
#undef CMP

  #pragma unroll
  for (int mi=0;mi<4;mi++)
    #pragma unroll
    for (int ni=0;ni<4;ni++)
      #pragma unroll
      for (int r=0;r<4;r++){
        size_t row = m0 + wm*64 + mi*16 + quad*4 + r;
        int    col = (int)n0 + wn*64 + ni*16 + l15;
        out0[row*1024 + col] = acc[mi][ni][r];
      }
}

// ---------------- causal depthwise conv1d (DCONV=4), per-batch ----------------
__global__ __launch_bounds__(256) void conv_kernel(const u16* __restrict__ xraw,
                                                   const float* __restrict__ cw,
                                                   const float* __restrict__ cb,
                                                   u16* __restrict__ xconv){
  const int c  = blockIdx.x*256 + threadIdx.x;
  const int t0 = blockIdx.y*8;
  const float w0=cw[c*4+0], w1=cw[c*4+1], w2=cw[c*4+2], w3=cw[c*4+3], bias=cb[c];
  const size_t base = (size_t)c;
  float h0 = (t0>=3) ? bf2f(xraw[base + (size_t)(t0-3)*5120]) : 0.f;
  float h1 = (t0>=2) ? bf2f(xraw[base + (size_t)(t0-2)*5120]) : 0.f;
  float h2 = (t0>=1) ? bf2f(xraw[base + (size_t)(t0-1)*5120]) : 0.f;
  #pragma unroll
  for (int i=0;i<8;i++){
    float x = bf2f(xraw[base + (size_t)(t0+i)*5120]);
    float o = w0*h0 + w1*h1 + w2*h2 + w3*x + bias;
    xconv[base + (size_t)(t0+i)*5120] = f2bf(o);
    h0=h1; h1=h2; h2=x;
  }
}

// ---------------- chunk kernel 1 (per-batch): Y_diag + D*x, states, dc ----------------
__global__ __launch_bounds__(256,1) void chunk1_kernel(const u16* __restrict__ xconv,
                                                       const float* __restrict__ dtb,
                                                       const float* __restrict__ Dvec,
                                                       float* __restrict__ ypart,
                                                       float* __restrict__ states,
                                                       float* __restrict__ dcb){
  __shared__ u16 Ps[128*136];
  __shared__ u16 XT[32*136];
  __shared__ u16 BT[64*136];
  __shared__ float Acum[128];
  __shared__ float decay[128];

  const int tid = threadIdx.x;
  const int lane = tid & 63;
  const int w = tid >> 6, quad = lane >> 4, l15 = lane & 15;
  const int blk = blockIdx.x;               // c*32 + h
  const int h = blk & 31, c = blk >> 5;
  const size_t tok0 = (size_t)c*128;
  const size_t xbase = tok0 * 5120;

  float mdt = 0.f;
  if (tid < 128) mdt = -dtb[(tok0 + tid)*32 + h];

  #pragma unroll
  for (int p=0;p<2;p++){
    int idx = p*256 + tid;
    int row = idx >> 2, col = (idx & 3)*8;
    u32x4 v = *(const u32x4*)(xconv + xbase + (size_t)row*5120 + h*32 + col);
    const u16* pv = (const u16*)&v;
    #pragma unroll
    for (int j=0;j<8;j++) XT[(col+j)*136 + row] = pv[j];
  }
  #pragma unroll
  for (int p=0;p<4;p++){
    int idx = p*256 + tid;
    int row = idx >> 3, col = (idx & 7)*8;
    u32x4 v = *(const u32x4*)(xconv + xbase + (size_t)row*5120 + 1024 + h*64 + col);
    const u16* pv = (const u16*)&v;
    #pragma unroll
    for (int j=0;j<8;j++) BT[(col+j)*136 + row] = pv[j];
  }
  if (tid < 128) Acum[tid] = mdt;
  __syncthreads();
  float run = mdt;
  for (int off=1; off<128; off<<=1){
    float add = 0.f;
    if (tid < 128 && tid >= off) add = Acum[tid-off];
    __syncthreads();
    if (tid < 128){ run += add; Acum[tid] = run; }
    __syncthreads();
  }
  float Alast = Acum[127];
  if (tid < 128) decay[tid] = __expf(Alast - Acum[tid]);
  if (tid == 0)  dcb[blk] = __expf(Alast);

  const int wm = w >> 1, wn = w & 1;
  f32x4 g[4][4];
  #pragma unroll
  for (int i=0;i<4;i++)
    #pragma unroll
    for (int j=0;j<4;j++){ f32x4 z = {0.f,0.f,0.f,0.f}; g[i][j] = z; }
  #pragma unroll
  for (int kk=0; kk<2; kk++){
    bf16x8 av[4], bv[4];
    #pragma unroll
    for (int mi=0;mi<4;mi++){
      int row = wm*64 + mi*16 + l15;
      av[mi] = *(const bf16x8*)(xconv + xbase + (size_t)row*5120 + 3072 + h*64 + kk*32 + quad*8);
    }
    #pragma unroll
    for (int ni=0;ni<4;ni++){
      int row = wn*64 + ni*16 + l15;
      bv[ni] = *(const bf16x8*)(xconv + xbase + (size_t)row*5120 + 1024 + h*64 + kk*32 + quad*8);
    }
    #pragma unroll
    for (int mi=0;mi<4;mi++)
      #pragma unroll
      for (int ni=0;ni<4;ni++)
        g[mi][ni] = mfma16(av[mi], bv[ni], g[mi][ni]);
  }
  #pragma unroll
  for (int mi=0;mi<4;mi++){
    int rowb = wm*64 + mi*16 + quad*4;
    #pragma unroll
    for (int ni=0;ni<4;ni++){
      int col = wn*64 + ni*16 + l15;
      float ac = Acum[col];
      #pragma unroll
      for (int r=0;r<4;r++){
        int row = rowb + r;
        float val = 0.f;
        if (col <= row) val = g[mi][ni][r] * __expf(Acum[row] - ac);
        Ps[row*136 + col] = f2bf(val);
      }
    }
  }
  __syncthreads();

  f32x4 yd[2][2];
  #pragma unroll
  for (int i=0;i<2;i++)
    #pragma unroll
    for (int j=0;j<2;j++){ f32x4 z = {0.f,0.f,0.f,0.f}; yd[i][j] = z; }
  #pragma unroll
  for (int kk=0;kk<4;kk++){
    bf16x8 av[2], bv[2];
    #pragma unroll
    for (int mi=0;mi<2;mi++) av[mi] = *(const bf16x8*)&Ps[(w*32+mi*16+l15)*136 + kk*32 + quad*8];
    #pragma unroll
    for (int ni=0;ni<2;ni++) bv[ni] = *(const bf16x8*)&XT[(ni*16+l15)*136 + kk*32 + quad*8];
    #pragma unroll
    for (int mi=0;mi<2;mi++)
      #pragma unroll
      for (int ni=0;ni<2;ni++)
        yd[mi][ni] = mfma16(av[mi], bv[ni], yd[mi][ni]);
  }
  float Dh = Dvec[h];
  #pragma unroll
  for (int mi=0;mi<2;mi++)
    #pragma unroll
    for (int ni=0;ni<2;ni++)
      #pragma unroll
      for (int r=0;r<4;r++){
        int row = w*32 + mi*16 + quad*4 + r;
        int col = ni*16 + l15;
        float xval = bf2f(XT[col*136 + row]);
        ypart[(tok0+row)*1024 + h*32 + col] = yd[mi][ni][r] + Dh*xval;
      }

  const int wm2 = w >> 1, wn2 = w & 1;
  f32x4 st[2];
  { f32x4 z = {0.f,0.f,0.f,0.f}; st[0]=z; st[1]=z; }
  #pragma unroll
  for (int kk=0;kk<4;kk++){
    bf16x8 av;
    {
      u32x4 xv = *(const u32x4*)&XT[(wm2*16+l15)*136 + kk*32 + quad*8];
      const u16* xp = (const u16*)&xv;
      #pragma unroll
      for (int j=0;j<8;j++) ((__bf16*)&av)[j] = (__bf16)(bf2f(xp[j]) * decay[kk*32 + quad*8 + j]);
    }
    bf16x8 bv[2];
    #pragma unroll
    for (int ni=0;ni<2;ni++) bv[ni] = *(const bf16x8*)&BT[(wn2*32+ni*16+l15)*136 + kk*32 + quad*8];
    #pragma unroll
    for (int ni=0;ni<2;ni++) st[ni] = mfma16(av, bv[ni], st[ni]);
  }
  size_t sbase = (size_t)blk * 2048;
  #pragma unroll
  for (int ni=0;ni<2;ni++)
    #pragma unroll
    for (int r=0;r<4;r++){
      int row = wm2*16 + quad*4 + r;
      int col = wn2*32 + ni*16 + l15;
      states[sbase + row*64 + col] = st[ni][r];
    }
}

// ---------------- inter-chunk scan (per-batch, in-place states -> prevs) ----------------
// preload all 64 chunk-values into registers so the 64 loads pipeline (the old
// load->store->load chain was latency-serialized: compiler couldn't disprove aliasing)
__global__ __launch_bounds__(256) void scan_kernel(float* __restrict__ states,
                                                   const float* __restrict__ dcb){
  const int h = blockIdx.x >> 3;
  const int part = blockIdx.x & 7;
  const int pn = part*256 + threadIdx.x;
  float r[64];
  #pragma unroll
  for (int c=0;c<64;c++) r[c] = states[((size_t)(c*32 + h))*2048 + pn];
  float S = 0.f;
  #pragma unroll
  for (int c=0;c<64;c++){
    float stv = r[c];
    states[((size_t)(c*32 + h))*2048 + pn] = S;
    S = S*dcb[c*32 + h] + stv;
  }
}

// ---------------- chunk kernel 3 (per-batch): Y_off + gate ----------------
__global__ __launch_bounds__(256,1) void chunk3_kernel(const u16* __restrict__ xconv,
                                                       const float* __restrict__ dtb,
                                                       const float* __restrict__ prevs,
                                                       const float* __restrict__ ypart,
                                                       const u16* __restrict__ gate,
                                                       u16* __restrict__ yg){
  __shared__ u16 Pv[32*72];
  __shared__ float Acum[128];
  const int tid = threadIdx.x;
  const int lane = tid & 63;
  const int w = tid >> 6, quad = lane >> 4, l15 = lane & 15;
  const int blk = blockIdx.x;
  const int h = blk & 31, c = blk >> 5;
  const size_t tok0 = (size_t)c*128;
  const size_t xbase = tok0 * 5120;

  float mdt = 0.f;
  if (tid < 128) mdt = -dtb[(tok0 + tid)*32 + h];
  size_t sbase = (size_t)blk * 2048;
  #pragma unroll
  for (int p=0;p<8;p++){
    int i = p*256 + tid;
    int pp = i >> 6, nn = i & 63;
    Pv[pp*72 + nn] = f2bf(prevs[sbase + i]);
  }
  if (tid < 128) Acum[tid] = mdt;
  __syncthreads();
  float run = mdt;
  for (int off=1; off<128; off<<=1){
    float add = 0.f;
    if (tid < 128 && tid >= off) add = Acum[tid-off];
    __syncthreads();
    if (tid < 128){ run += add; Acum[tid] = run; }
    __syncthreads();
  }

  f32x4 yo[2][2];
  #pragma unroll
  for (int i=0;i<2;i++)
    #pragma unroll
    for (int j=0;j<2;j++){ f32x4 z = {0.f,0.f,0.f,0.f}; yo[i][j] = z; }
  #pragma unroll
  for (int kk=0;kk<2;kk++){
    bf16x8 av[2], bv[2];
    #pragma unroll
    for (int mi=0;mi<2;mi++){
      int row = w*32 + mi*16 + l15;
      av[mi] = *(const bf16x8*)(xconv + xbase + (size_t)row*5120 + 3072 + h*64 + kk*32 + quad*8);
    }
    #pragma unroll
    for (int ni=0;ni<2;ni++) bv[ni] = *(const bf16x8*)&Pv[(ni*16+l15)*72 + kk*32 + quad*8];
    #pragma unroll
    for (int mi=0;mi<2;mi++)
      #pragma unroll
      for (int ni=0;ni<2;ni++)
        yo[mi][ni] = mfma16(av[mi], bv[ni], yo[mi][ni]);
  }
  #pragma unroll
  for (int mi=0;mi<2;mi++)
    #pragma unroll
    for (int ni=0;ni<2;ni++)
      #pragma unroll
      for (int r=0;r<4;r++){
        int row = w*32 + mi*16 + quad*4 + r;
        int col = ni*16 + l15;
        size_t gi = (tok0+row)*1024 + h*32 + col;
        float val = (ypart[gi] + __expf(Acum[row]) * yo[mi][ni][r]) * bf2f(gate[gi]);
        yg[gi] = f2bf(val);
      }
}

// ---------------- host ----------------
extern "C" void kernel_launch(void* const* d_in, const int* in_sizes, int n_in,
                              void* d_out, int out_size, void* d_ws, size_t ws_size,
                              hipStream_t stream){
  (void)out_size; (void)ws_size;
  static const int want[7] = {16777216, 6324224, 20480, 5120, 1024, 32, 1048576};
  const void* src[7] = {nullptr,nullptr,nullptr,nullptr,nullptr,nullptr,nullptr};
  if (n_in >= 7){
    for (int i=0;i<7;i++)
      for (int j=0;j<n_in;j++)
        if (in_sizes[j] == want[i]){ src[i] = d_in[j]; break; }
  }
  bool ok = true;
  for (int i=0;i<7;i++) if (!src[i]) ok = false;
  if (!ok) for (int i=0;i<7;i++) src[i] = d_in[i];
  const float* u      = (const float*)src[0];
  const float* W_in   = (const float*)src[1];
  const float* conv_w = (const float*)src[2];
  const float* conv_b = (const float*)src[3];
  const float* z_bias = (const float*)src[4];
  const float* Dvec   = (const float*)src[5];
  const float* W_out  = (const float*)src[6];
  float* out = (float*)d_out;                             // fp32 output

  // workspace: 240 MiB total
  char* p = (char*)d_ws;
  u16* wi_bf   = (u16*)p;   p += (size_t)6144*1024*2;     // 12 MiB
  u16* wo_bf   = (u16*)p;   p += (size_t)1024*1024*2;     // 2 MiB
  u16* u_bf    = (u16*)p;   p += (size_t)16384*1024*2;    // 32 MiB
  float* dtb   = (float*)p; p += (size_t)16384*32*4;      // 2 MiB
  float* dcb   = (float*)p; p += (size_t)4096*4;          // 16 KiB
  u16* gate    = (u16*)p;   p += (size_t)8192*1024*2;     // 16 MiB (per-batch)
  u16* yg      = (u16*)p;   p += (size_t)8192*1024*2;     // 16 MiB (per-batch)
  char* xbcA   = p;         p += (size_t)8192*5120*2;     // 80 MiB (per-batch)
  u16* xconv   = (u16*)p;   p += (size_t)8192*5120*2;     // 80 MiB (per-batch)

  u16*   xbc_raw = (u16*)xbcA;
  float* ypart   = (float*)xbcA;                          // alias (xbc_raw dead after conv)
  float* states  = (float*)(xbcA + (size_t)8192*1024*4);  // alias, +32 MiB

  cvt_kernel<<<16384, 256, 0, stream>>>(u,     u_bf,  16384*1024/4);
  cvt_kernel<<<6144,  256, 0, stream>>>(W_in,  wi_bf, 6144*1024/4);
  cvt_kernel<<<1024,  256, 0, stream>>>(W_out, wo_bf, 1024*1024/4);
  dt_kernel<<<2048, 256, 0, stream>>>(u, W_in, dtb);

  for (int b = 0; b < 2; b++){
    const u16* ub_bf = u_bf + (size_t)b*8192*1024;
    float*     dtb_b = dtb  + (size_t)b*8192*32;
    float*     dcb_b = dcb  + (size_t)b*2048;
    float*     out_b = out  + (size_t)b*8192*1024;
    gemm_in<<<dim3(48,64), 256, 0, stream>>>(ub_bf, wi_bf, xbc_raw, gate, z_bias);
    conv_kernel<<<dim3(20,1024), 256, 0, stream>>>(xbc_raw, conv_w, conv_b, xconv);
    chunk1_kernel<<<2048, 256, 0, stream>>>(xconv, dtb_b, Dvec, ypart, states, dcb_b);
    scan_kernel<<<256, 256, 0, stream>>>(states, dcb_b);
    chunk3_kernel<<<2048, 256, 0, stream>>>(xconv, dtb_b, states, ypart, gate, yg);
    gemm_out<<<dim3(8,64), 256, 0, stream>>>(yg, wo_bf, out_b);
  }
}

// Round 7
// 734.246 us; speedup vs baseline: 1.1514x; 1.1514x over previous
//
#include <hip/hip_runtime.h>

typedef unsigned short u16;
typedef unsigned int   u32;
typedef __bf16  bf16x8 __attribute__((ext_vector_type(8)));
typedef float   f32x4  __attribute__((ext_vector_type(4)));
typedef unsigned int u32x4 __attribute__((ext_vector_type(4)));
typedef unsigned int u32x2 __attribute__((ext_vector_type(2)));

__device__ __forceinline__ float bf2f(u16 h){ return __uint_as_float(((u32)h)<<16); }
__device__ __forceinline__ u16 f2bf(float f){
  u32 u = __float_as_uint(f);
  u += 0x7FFFu + ((u>>16)&1u);
  return (u16)(u>>16);
}
__device__ __forceinline__ f32x4 mfma16(bf16x8 a, bf16x8 b, f32x4 c){
  return __builtin_amdgcn_mfma_f32_16x16x32_bf16(a,b,c,0,0,0);
}
// async global->LDS, 16B per lane (dest = wave-uniform base + lane*16)
__device__ __forceinline__ void ld16_lds(const u16* g, u16* l){
  __builtin_amdgcn_global_load_lds((const __attribute__((address_space(1))) u32*)g,
                                   (__attribute__((address_space(3))) u32*)l, 16, 0, 0);
}

// ---------------- fp32 -> bf16 convert (4 elems/thread) ----------------
__global__ __launch_bounds__(256) void cvt_kernel(const float* __restrict__ in,
                                                  u16* __restrict__ out, int n4){
  int i = blockIdx.x*256 + threadIdx.x;
  if (i < n4){
    float4 v = ((const float4*)in)[i];
    u32 p0 = (u32)f2bf(v.x) | ((u32)f2bf(v.y)<<16);
    u32 p1 = (u32)f2bf(v.z) | ((u32)f2bf(v.w)<<16);
    u32x2 pv = {p0, p1};
    *(u32x2*)(out + (size_t)i*4) = pv;
  }
}

// ---------------- dt = softplus(u @ W_A^T) in fp32 (full 16384 tokens) ----------------
__global__ __launch_bounds__(256) void dt_kernel(const float* __restrict__ u,
                                                 const float* __restrict__ Win,
                                                 float* __restrict__ dtb){
  __shared__ float us[8][1028];
  const int tid = threadIdx.x;
  const size_t t0 = (size_t)blockIdx.x*8;
  for (int i=tid; i<2048; i+=256){
    int row = i>>8, col = (i&255)*4;
    *(float4*)&us[row][col] = *(const float4*)(u + (t0+row)*1024 + col);
  }
  __syncthreads();
  const int tok = tid & 7, h = tid >> 3;
  const float* wp = Win + (size_t)(6144+h)*1024;
  float s0=0.f,s1=0.f,s2=0.f,s3=0.f;
  for (int k=0;k<1024;k+=4){
    float4 a  = *(const float4*)&us[tok][k];
    float4 wv = *(const float4*)&wp[k];
    s0 += a.x*wv.x; s1 += a.y*wv.y; s2 += a.z*wv.z; s3 += a.w*wv.w;
  }
  float s = (s0+s1)+(s2+s3);
  dtb[(t0+tok)*32 + h] = (s > 15.f) ? s : log1pf(expf(s));
}

// ---------------- in_proj GEMM (bf16 NT, 128x128 tile, BK=64, 2-phase) ----------------
// R5-proven config (136us, conflicts=0): single-buffer BK=64, natural block map,
// swizzle slot' = slot ^ (row&7) via inverse-swizzled global SOURCE + swizzled read.
// R6 showed explicit dbuf regresses (halves blocks/CU; inter-block TLP IS the pipeline).
__global__ __launch_bounds__(256,2) void gemm_in(const u16* __restrict__ A,
                                                 const u16* __restrict__ Bw,
                                                 u16* __restrict__ out0,
                                                 u16* __restrict__ out1,
                                                 const float* __restrict__ zb){
  __shared__ u16 As[128*64];
  __shared__ u16 Bs[128*64];
  const int tid  = threadIdx.x;
  const int lane = tid & 63;
  const int w = tid >> 6, wm = w >> 1, wn = w & 1;
  const int quad = lane >> 4, l15 = lane & 15;
  const size_t m0 = (size_t)blockIdx.y*128, n0 = (size_t)blockIdx.x*128;

  f32x4 acc[4][4];
  #pragma unroll
  for (int i=0;i<4;i++)
    #pragma unroll
    for (int j=0;j<4;j++){ f32x4 z = {0.f,0.f,0.f,0.f}; acc[i][j] = z; }

  const int srow    = w*32 + (lane>>3);
  const int scol_sw = ((lane&7) ^ (lane>>3))*8;
  const u16* gA = A  + (m0+srow)*1024 + scol_sw;
  const u16* gB = Bw + (n0+srow)*1024 + scol_sw;
  u16* lA = As + w*2048;
  u16* lB = Bs + w*2048;

  for (int k0 = 0; k0 < 1024; k0 += 64){
    __syncthreads();
    ld16_lds(gA,           lA);
    ld16_lds(gA +  8*1024, lA + 512);
    ld16_lds(gA + 16*1024, lA + 1024);
    ld16_lds(gA + 24*1024, lA + 1536);
    ld16_lds(gB,           lB);
    ld16_lds(gB +  8*1024, lB + 512);
    ld16_lds(gB + 16*1024, lB + 1024);
    ld16_lds(gB + 24*1024, lB + 1536);
    gA += 64; gB += 64;
    __syncthreads();
    #pragma unroll
    for (int kk=0;kk<2;kk++){
      bf16x8 av[4], bv[4];
      #pragma unroll
      for (int mi=0;mi<4;mi++){
        int row = wm*64+mi*16+l15;
        av[mi] = *(const bf16x8*)&As[row*64 + (((kk*4+quad) ^ (l15&7))*8)];
      }
      #pragma unroll
      for (int ni=0;ni<4;ni++){
        int row = wn*64+ni*16+l15;
        bv[ni] = *(const bf16x8*)&Bs[row*64 + (((kk*4+quad) ^ (l15&7))*8)];
      }
      #pragma unroll
      for (int mi=0;mi<4;mi++)
        #pragma unroll
        for (int ni=0;ni<4;ni++)
          acc[mi][ni] = mfma16(av[mi], bv[ni], acc[mi][ni]);
    }
  }

  #pragma unroll
  for (int mi=0;mi<4;mi++){
    #pragma unroll
    for (int ni=0;ni<4;ni++){
      #pragma unroll
      for (int r=0;r<4;r++){
        size_t row = m0 + wm*64 + mi*16 + quad*4 + r;
        int    col = (int)n0 + wn*64 + ni*16 + l15;
        float v = acc[mi][ni][r];
        if (col < 5120){
          out0[row*5120 + col] = f2bf(v);
        } else {
          int ch = col - 5120;
          float z = v + zb[ch];
          float sg = z / (1.f + __expf(-z));
          out1[row*1024 + ch] = f2bf(sg);
        }
      }
    }
  }
}

// ---------------- out GEMM (bf16 NT, BK=64, 2-phase, fp32 store) ----------------
__global__ __launch_bounds__(256,2) void gemm_out(const u16* __restrict__ A,
                                                  const u16* __restrict__ Bw,
                                                  float* __restrict__ out0){
  __shared__ u16 As[128*64];
  __shared__ u16 Bs[128*64];
  const int tid  = threadIdx.x;
  const int lane = tid & 63;
  const int w = tid >> 6, wm = w >> 1, wn = w & 1;
  const int quad = lane >> 4, l15 = lane & 15;
  const size_t m0 = (size_t)blockIdx.y*128, n0 = (size_t)blockIdx.x*128;

  f32x4 acc[4][4];
  #pragma unroll
  for (int i=0;i<4;i++)
    #pragma unroll
    for (int j=0;j<4;j++){ f32x4 z = {0.f,0.f,0.f,0.f}; acc[i][j] = z; }

  const int srow    = w*32 + (lane>>3);
  const int scol_sw = ((lane&7) ^ (lane>>3))*8;
  const u16* gA = A  + (m0+srow)*1024 + scol_sw;
  const u16* gB = Bw + (n0+srow)*1024 + scol_sw;
  u16* lA = As + w*2048;
  u16* lB = Bs + w*2048;

  for (int k0 = 0; k0 < 1024; k0 += 64){
    __syncthreads();
    ld16_lds(gA,           lA);
    ld16_lds(gA +  8*1024, lA + 512);
    ld16_lds(gA + 16*1024, lA + 1024);
    ld16_lds(gA + 24*1024, lA + 1536);
    ld16_lds(gB,           lB);
    ld16_lds(gB +  8*1024, lB + 512);
    ld16_lds(gB + 16*1024, lB + 1024);
    ld16_lds(gB + 24*1024, lB + 1536);
    gA += 64; gB += 64;
    __syncthreads();
    #pragma unroll
    for (int kk=0;kk<2;kk++){
      bf16x8 av[4], bv[4];
      #pragma unroll
      for (int mi=0;mi<4;mi++){
        int row = wm*64+mi*16+l15;
        av[mi] = *(const bf16x8*)&As[row*64 + (((kk*4+quad) ^ (l15&7))*8)];
      }
      #pragma unroll
      for (int ni=0;ni<4;ni++){
        int row = wn*64+ni*16+l15;
        bv[ni] = *(const bf16x8*)&Bs[row*64 + (((kk*4+quad) ^ (l15&7))*8)];
      }
      #pragma unroll
      for (int mi=0;mi<4;mi++)
        #pragma unroll
        for (int ni=0;ni<4;ni++)
          acc[mi][ni] = mfma16(av[mi], bv[ni], acc[mi][ni]);
    }
  }

  #pragma unroll
  for (int mi=0;mi<4;mi++)
    #pragma unroll
    for (int ni=0;ni<4;ni++)
      #pragma unroll
      for (int r=0;r<4;r++){
        size_t row = m0 + wm*64 + mi*16 + quad*4 + r;
        int    col = (int)n0 + wn*64 + ni*16 + l15;
        out0[row*1024 + col] = acc[mi][ni][r];
      }
}

// ---------------- causal depthwise conv1d (DCONV=4), per-batch ----------------
// Vectorized: 4 channels/thread (u32x2 8B loads/stores -> 512B/wave) x 16 tokens
// (halo re-read 37% -> 19%). Was scalar bf16 (128B/wave, Common-mistake #2).
__global__ __launch_bounds__(256) void conv_kernel(const u16* __restrict__ xraw,
                                                   const float* __restrict__ cw,
                                                   const float* __restrict__ cb,
                                                   u16* __restrict__ xconv){
  const int c4 = blockIdx.x*256 + threadIdx.x;   // 0..1279
  const int ch = c4*4;
  const int t0 = blockIdx.y*16;
  float w0[4], w1[4], w2[4], w3[4], bs[4];
  #pragma unroll
  for (int q=0;q<4;q++){
    float4 wv = *(const float4*)&cw[(ch+q)*4];
    w0[q]=wv.x; w1[q]=wv.y; w2[q]=wv.z; w3[q]=wv.w;
    bs[q]=cb[ch+q];
  }
  const size_t base = (size_t)ch;
  float h0[4], h1[4], h2[4];
  if (t0 >= 3){
    u32x2 v0 = *(const u32x2*)(xraw + base + (size_t)(t0-3)*5120);
    u32x2 v1 = *(const u32x2*)(xraw + base + (size_t)(t0-2)*5120);
    u32x2 v2 = *(const u32x2*)(xraw + base + (size_t)(t0-1)*5120);
    const u16* p0=(const u16*)&v0; const u16* p1=(const u16*)&v1; const u16* p2=(const u16*)&v2;
    #pragma unroll
    for (int q=0;q<4;q++){ h0[q]=bf2f(p0[q]); h1[q]=bf2f(p1[q]); h2[q]=bf2f(p2[q]); }
  } else {
    #pragma unroll
    for (int q=0;q<4;q++){ h0[q]=0.f; h1[q]=0.f; h2[q]=0.f; }
  }
  #pragma unroll
  for (int i=0;i<16;i++){
    u32x2 v = *(const u32x2*)(xraw + base + (size_t)(t0+i)*5120);
    const u16* p = (const u16*)&v;
    u16 o[4];
    #pragma unroll
    for (int q=0;q<4;q++){
      float x = bf2f(p[q]);
      float r = w0[q]*h0[q] + w1[q]*h1[q] + w2[q]*h2[q] + w3[q]*x + bs[q];
      o[q] = f2bf(r);
      h0[q]=h1[q]; h1[q]=h2[q]; h2[q]=x;
    }
    u32x2 ov = { (u32)o[0] | ((u32)o[1]<<16), (u32)o[2] | ((u32)o[3]<<16) };
    *(u32x2*)(xconv + base + (size_t)(t0+i)*5120) = ov;
  }
}

// ---------------- chunk kernel 1 (per-batch): Y_diag + D*x, states, dc ----------------
__global__ __launch_bounds__(256,1) void chunk1_kernel(const u16* __restrict__ xconv,
                                                       const float* __restrict__ dtb,
                                                       const float* __restrict__ Dvec,
                                                       float* __restrict__ ypart,
                                                       float* __restrict__ states,
                                                       float* __restrict__ dcb){
  __shared__ u16 Ps[128*136];
  __shared__ u16 XT[32*136];
  __shared__ u16 BT[64*136];
  __shared__ float Acum[128];
  __shared__ float decay[128];

  const int tid = threadIdx.x;
  const int lane = tid & 63;
  const int w = tid >> 6, quad = lane >> 4, l15 = lane & 15;
  const int blk = blockIdx.x;               // c*32 + h
  const int h = blk & 31, c = blk >> 5;
  const size_t tok0 = (size_t)c*128;
  const size_t xbase = tok0 * 5120;

  float mdt = 0.f;
  if (tid < 128) mdt = -dtb[(tok0 + tid)*32 + h];

  #pragma unroll
  for (int p=0;p<2;p++){
    int idx = p*256 + tid;
    int row = idx >> 2, col = (idx & 3)*8;
    u32x4 v = *(const u32x4*)(xconv + xbase + (size_t)row*5120 + h*32 + col);
    const u16* pv = (const u16*)&v;
    #pragma unroll
    for (int j=0;j<8;j++) XT[(col+j)*136 + row] = pv[j];
  }
  #pragma unroll
  for (int p=0;p<4;p++){
    int idx = p*256 + tid;
    int row = idx >> 3, col = (idx & 7)*8;
    u32x4 v = *(const u32x4*)(xconv + xbase + (size_t)row*5120 + 1024 + h*64 + col);
    const u16* pv = (const u16*)&v;
    #pragma unroll
    for (int j=0;j<8;j++) BT[(col+j)*136 + row] = pv[j];
  }
  // wave-level inclusive scan of mdt over 128 tokens (2 barriers vs 14)
  if (tid < 128){
    float v = mdt;
    #pragma unroll
    for (int d=1; d<64; d<<=1){
      float t = __shfl_up(v, d, 64);
      if (lane >= d) v += t;
    }
    Acum[tid] = v;
  }
  __syncthreads();
  if (tid >= 64 && tid < 128) Acum[tid] += Acum[63];
  __syncthreads();
  float Alast = Acum[127];
  if (tid < 128) decay[tid] = __expf(Alast - Acum[tid]);
  if (tid == 0)  dcb[blk] = __expf(Alast);

  const int wm = w >> 1, wn = w & 1;
  f32x4 g[4][4];
  #pragma unroll
  for (int i=0;i<4;i++)
    #pragma unroll
    for (int j=0;j<4;j++){ f32x4 z = {0.f,0.f,0.f,0.f}; g[i][j] = z; }
  #pragma unroll
  for (int kk=0; kk<2; kk++){
    bf16x8 av[4], bv[4];
    #pragma unroll
    for (int mi=0;mi<4;mi++){
      int row = wm*64 + mi*16 + l15;
      av[mi] = *(const bf16x8*)(xconv + xbase + (size_t)row*5120 + 3072 + h*64 + kk*32 + quad*8);
    }
    #pragma unroll
    for (int ni=0;ni<4;ni++){
      int row = wn*64 + ni*16 + l15;
      bv[ni] = *(const bf16x8*)(xconv + xbase + (size_t)row*5120 + 1024 + h*64 + kk*32 + quad*8);
    }
    #pragma unroll
    for (int mi=0;mi<4;mi++)
      #pragma unroll
      for (int ni=0;ni<4;ni++)
        g[mi][ni] = mfma16(av[mi], bv[ni], g[mi][ni]);
  }
  #pragma unroll
  for (int mi=0;mi<4;mi++){
    int rowb = wm*64 + mi*16 + quad*4;
    #pragma unroll
    for (int ni=0;ni<4;ni++){
      int col = wn*64 + ni*16 + l15;
      float ac = Acum[col];
      #pragma unroll
      for (int r=0;r<4;r++){
        int row = rowb + r;
        float val = 0.f;
        if (col <= row) val = g[mi][ni][r] * __expf(Acum[row] - ac);
        Ps[row*136 + col] = f2bf(val);
      }
    }
  }
  __syncthreads();

  f32x4 yd[2][2];
  #pragma unroll
  for (int i=0;i<2;i++)
    #pragma unroll
    for (int j=0;j<2;j++){ f32x4 z = {0.f,0.f,0.f,0.f}; yd[i][j] = z; }
  #pragma unroll
  for (int kk=0;kk<4;kk++){
    bf16x8 av[2], bv[2];
    #pragma unroll
    for (int mi=0;mi<2;mi++) av[mi] = *(const bf16x8*)&Ps[(w*32+mi*16+l15)*136 + kk*32 + quad*8];
    #pragma unroll
    for (int ni=0;ni<2;ni++) bv[ni] = *(const bf16x8*)&XT[(ni*16+l15)*136 + kk*32 + quad*8];
    #pragma unroll
    for (int mi=0;mi<2;mi++)
      #pragma unroll
      for (int ni=0;ni<2;ni++)
        yd[mi][ni] = mfma16(av[mi], bv[ni], yd[mi][ni]);
  }
  float Dh = Dvec[h];
  #pragma unroll
  for (int mi=0;mi<2;mi++)
    #pragma unroll
    for (int ni=0;ni<2;ni++)
      #pragma unroll
      for (int r=0;r<4;r++){
        int row = w*32 + mi*16 + quad*4 + r;
        int col = ni*16 + l15;
        float xval = bf2f(XT[col*136 + row]);
        ypart[(tok0+row)*1024 + h*32 + col] = yd[mi][ni][r] + Dh*xval;
      }

  const int wm2 = w >> 1, wn2 = w & 1;
  f32x4 st[2];
  { f32x4 z = {0.f,0.f,0.f,0.f}; st[0]=z; st[1]=z; }
  #pragma unroll
  for (int kk=0;kk<4;kk++){
    bf16x8 av;
    {
      u32x4 xv = *(const u32x4*)&XT[(wm2*16+l15)*136 + kk*32 + quad*8];
      const u16* xp = (const u16*)&xv;
      #pragma unroll
      for (int j=0;j<8;j++) ((__bf16*)&av)[j] = (__bf16)(bf2f(xp[j]) * decay[kk*32 + quad*8 + j]);
    }
    bf16x8 bv[2];
    #pragma unroll
    for (int ni=0;ni<2;ni++) bv[ni] = *(const bf16x8*)&BT[(wn2*32+ni*16+l15)*136 + kk*32 + quad*8];
    #pragma unroll
    for (int ni=0;ni<2;ni++) st[ni] = mfma16(av, bv[ni], st[ni]);
  }
  size_t sbase = (size_t)blk * 2048;
  #pragma unroll
  for (int ni=0;ni<2;ni++)
    #pragma unroll
    for (int r=0;r<4;r++){
      int row = wm2*16 + quad*4 + r;
      int col = wn2*32 + ni*16 + l15;
      states[sbase + row*64 + col] = st[ni][r];
    }
}

// ---------------- inter-chunk scan (per-batch, in-place states -> prevs) ----------------
__global__ __launch_bounds__(256) void scan_kernel(float* __restrict__ states,
                                                   const float* __restrict__ dcb){
  const int h = blockIdx.x >> 3;
  const int part = blockIdx.x & 7;
  const int pn = part*256 + threadIdx.x;
  float r[64];
  #pragma unroll
  for (int c=0;c<64;c++) r[c] = states[((size_t)(c*32 + h))*2048 + pn];
  float S = 0.f;
  #pragma unroll
  for (int c=0;c<64;c++){
    float stv = r[c];
    states[((size_t)(c*32 + h))*2048 + pn] = S;
    S = S*dcb[c*32 + h] + stv;
  }
}

// ---------------- chunk kernel 3 (per-batch): Y_off + gate ----------------
__global__ __launch_bounds__(256,1) void chunk3_kernel(const u16* __restrict__ xconv,
                                                       const float* __restrict__ dtb,
                                                       const float* __restrict__ prevs,
                                                       const float* __restrict__ ypart,
                                                       const u16* __restrict__ gate,
                                                       u16* __restrict__ yg){
  __shared__ u16 Pv[32*72];
  __shared__ float Acum[128];
  const int tid = threadIdx.x;
  const int lane = tid & 63;
  const int w = tid >> 6, quad = lane >> 4, l15 = lane & 15;
  const int blk = blockIdx.x;
  const int h = blk & 31, c = blk >> 5;
  const size_t tok0 = (size_t)c*128;
  const size_t xbase = tok0 * 5120;

  float mdt = 0.f;
  if (tid < 128) mdt = -dtb[(tok0 + tid)*32 + h];
  size_t sbase = (size_t)blk * 2048;
  #pragma unroll
  for (int p=0;p<8;p++){
    int i = p*256 + tid;
    int pp = i >> 6, nn = i & 63;
    Pv[pp*72 + nn] = f2bf(prevs[sbase + i]);
  }
  // wave-level inclusive scan (2 barriers vs 14)
  if (tid < 128){
    float v = mdt;
    #pragma unroll
    for (int d=1; d<64; d<<=1){
      float t = __shfl_up(v, d, 64);
      if (lane >= d) v += t;
    }
    Acum[tid] = v;
  }
  __syncthreads();
  if (tid >= 64 && tid < 128) Acum[tid] += Acum[63];
  __syncthreads();

  f32x4 yo[2][2];
  #pragma unroll
  for (int i=0;i<2;i++)
    #pragma unroll
    for (int j=0;j<2;j++){ f32x4 z = {0.f,0.f,0.f,0.f}; yo[i][j] = z; }
  #pragma unroll
  for (int kk=0;kk<2;kk++){
    bf16x8 av[2], bv[2];
    #pragma unroll
    for (int mi=0;mi<2;mi++){
      int row = w*32 + mi*16 + l15;
      av[mi] = *(const bf16x8*)(xconv + xbase + (size_t)row*5120 + 3072 + h*64 + kk*32 + quad*8);
    }
    #pragma unroll
    for (int ni=0;ni<2;ni++) bv[ni] = *(const bf16x8*)&Pv[(ni*16+l15)*72 + kk*32 + quad*8];
    #pragma unroll
    for (int mi=0;mi<2;mi++)
      #pragma unroll
      for (int ni=0;ni<2;ni++)
        yo[mi][ni] = mfma16(av[mi], bv[ni], yo[mi][ni]);
  }
  #pragma unroll
  for (int mi=0;mi<2;mi++)
    #pragma unroll
    for (int ni=0;ni<2;ni++)
      #pragma unroll
      for (int r=0;r<4;r++){
        int row = w*32 + mi*16 + quad*4 + r;
        int col = ni*16 + l15;
        size_t gi = (tok0+row)*1024 + h*32 + col;
        float val = (ypart[gi] + __expf(Acum[row]) * yo[mi][ni][r]) * bf2f(gate[gi]);
        yg[gi] = f2bf(val);
      }
}

// ---------------- host ----------------
extern "C" void kernel_launch(void* const* d_in, const int* in_sizes, int n_in,
                              void* d_out, int out_size, void* d_ws, size_t ws_size,
                              hipStream_t stream){
  (void)out_size; (void)ws_size;
  static const int want[7] = {16777216, 6324224, 20480, 5120, 1024, 32, 1048576};
  const void* src[7] = {nullptr,nullptr,nullptr,nullptr,nullptr,nullptr,nullptr};
  if (n_in >= 7){
    for (int i=0;i<7;i++)
      for (int j=0;j<n_in;j++)
        if (in_sizes[j] == want[i]){ src[i] = d_in[j]; break; }
  }
  bool ok = true;
  for (int i=0;i<7;i++) if (!src[i]) ok = false;
  if (!ok) for (int i=0;i<7;i++) src[i] = d_in[i];
  const float* u      = (const float*)src[0];
  const float* W_in   = (const float*)src[1];
  const float* conv_w = (const float*)src[2];
  const float* conv_b = (const float*)src[3];
  const float* z_bias = (const float*)src[4];
  const float* Dvec   = (const float*)src[5];
  const float* W_out  = (const float*)src[6];
  float* out = (float*)d_out;                             // fp32 output

  // workspace: 240 MiB total
  char* p = (char*)d_ws;
  u16* wi_bf   = (u16*)p;   p += (size_t)6144*1024*2;     // 12 MiB
  u16* wo_bf   = (u16*)p;   p += (size_t)1024*1024*2;     // 2 MiB
  u16* u_bf    = (u16*)p;   p += (size_t)16384*1024*2;    // 32 MiB
  float* dtb   = (float*)p; p += (size_t)16384*32*4;      // 2 MiB
  float* dcb   = (float*)p; p += (size_t)4096*4;          // 16 KiB
  u16* gate    = (u16*)p;   p += (size_t)8192*1024*2;     // 16 MiB (per-batch)
  u16* yg      = (u16*)p;   p += (size_t)8192*1024*2;     // 16 MiB (per-batch)
  char* xbcA   = p;         p += (size_t)8192*5120*2;     // 80 MiB (per-batch)
  u16* xconv   = (u16*)p;   p += (size_t)8192*5120*2;     // 80 MiB (per-batch)

  u16*   xbc_raw = (u16*)xbcA;
  float* ypart   = (float*)xbcA;                          // alias (xbc_raw dead after conv)
  float* states  = (float*)(xbcA + (size_t)8192*1024*4);  // alias, +32 MiB

  cvt_kernel<<<16384, 256, 0, stream>>>(u,     u_bf,  16384*1024/4);
  cvt_kernel<<<6144,  256, 0, stream>>>(W_in,  wi_bf, 6144*1024/4);
  cvt_kernel<<<1024,  256, 0, stream>>>(W_out, wo_bf, 1024*1024/4);
  dt_kernel<<<2048, 256, 0, stream>>>(u, W_in, dtb);

  for (int b = 0; b < 2; b++){
    const u16* ub_bf = u_bf + (size_t)b*8192*1024;
    float*     dtb_b = dtb  + (size_t)b*8192*32;
    float*     dcb_b = dcb  + (size_t)b*2048;
    float*     out_b = out  + (size_t)b*8192*1024;
    gemm_in<<<dim3(48,64), 256, 0, stream>>>(ub_bf, wi_bf, xbc_raw, gate, z_bias);
    conv_kernel<<<dim3(5,512), 256, 0, stream>>>(xbc_raw, conv_w, conv_b, xconv);
    chunk1_kernel<<<2048, 256, 0, stream>>>(xconv, dtb_b, Dvec, ypart, states, dcb_b);
    scan_kernel<<<256, 256, 0, stream>>>(states, dcb_b);
    chunk3_kernel<<<2048, 256, 0, stream>>>(xconv, dtb_b, states, ypart, gate, yg);
    gemm_out<<<dim3(8,64), 256, 0, stream>>>(yg, wo_bf, out_b);
  }
}